// Round 6
// baseline (279.803 us; speedup 1.0000x reference)
//
#include <hip/hip_runtime.h>
#include <hip/hip_bf16.h>

// Problem constants
#define BB 4096
#define TT 16
#define HH 768
#define AA 128
#define VV 16
#define LL 2
#define NCHUNK 6        // K chunks of 128 (full K per block)
#define MT 64           // rows per tile

typedef __attribute__((ext_vector_type(8))) short short8v;   // 8 bf16 (4 VGPRs)
typedef __attribute__((ext_vector_type(4))) float float4v;   // MFMA C/D frag

// ws layout (int indices into d_ws):
//  [0..16]       offs (int)     bucket offsets
//  [64..4159]    rows (int)     bucketed row ids
//  [4160..8255]  Wuc  (float)   [V][A][L] = Wu@Wc^T
//  [8256..8287]  buc  (float)   [V][L]    = bu@Wc^T
//  [8448..]      Wdp  (ushort)  [V][6][A][128] bf16 transposed Wd (dense)
#define WS_OFFS 0
#define WS_ROWS 64
#define WS_WUC  4160
#define WS_BUC  8256
#define WS_WDP  8448

__device__ __forceinline__ unsigned short f2bf(float f) {
    __hip_bfloat16 h = __float2bfloat16(f);   // RNE
    return *reinterpret_cast<unsigned short*>(&h);
}

__device__ __forceinline__ float gelu_tanh(float z) {
    float y = 0.7978845608028654f * (z + 0.044715f * z * z * z);
    y = fminf(fmaxf(y, -15.f), 15.f);
    float e = __expf(2.f * y);
    float th = (e - 1.f) / (e + 1.f);
    return 0.5f * z * (1.f + th);
}

// ---------------- K1: prep (unchanged from R5)
// blocks 0..95   : Wdp[v][kc] = bf16 transpose of Wd chunk
// blocks 96..127 : Wuc[v][a][l] = (Wu[v] @ Wc^T)[a][l]
// block 128      : buc[v][l] = bu[v] @ Wc^T
// block 129      : bucket rows by variety
__global__ __launch_bounds__(256) void k_prep(
    const int*   __restrict__ variety_ids,
    const float* __restrict__ Wd,   // (V, H, A)
    const float* __restrict__ Wu,   // (V, A, H)
    const float* __restrict__ bu,   // (V, H)
    const float* __restrict__ Wc,   // (L, H)
    int* __restrict__ ws_i)
{
    __shared__ __align__(16) unsigned short Wds[128 * 136];
    __shared__ float sp0[256], sp1[256];
    __shared__ int hist[VV], hoff[VV + 1], hcur[VV];

    const int t = threadIdx.x;
    const int bid = blockIdx.x;
    unsigned short* wdp = (unsigned short*)(ws_i + WS_WDP);
    float* Wuc = (float*)(ws_i + WS_WUC);
    float* buc = (float*)(ws_i + WS_BUC);

    if (bid < 96) {
        const int v = bid / NCHUNK, kc = bid % NCHUNK;
        const float* wd = Wd + (size_t)v * HH * AA;
        const int ks0 = kc * 128;
        #pragma unroll
        for (int s = 0; s < 16; ++s) {
            int idx = t + s * 256;
            int hl  = idx >> 5;
            int a4  = idx & 31;
            float4 wv = *(const float4*)(wd + (size_t)(ks0 + hl) * AA + a4 * 4);
            Wds[(a4 * 4 + 0) * 136 + hl] = f2bf(wv.x);
            Wds[(a4 * 4 + 1) * 136 + hl] = f2bf(wv.y);
            Wds[(a4 * 4 + 2) * 136 + hl] = f2bf(wv.z);
            Wds[(a4 * 4 + 3) * 136 + hl] = f2bf(wv.w);
        }
        __syncthreads();
        unsigned short* dst = wdp + (size_t)(v * NCHUNK + kc) * AA * 128;
        #pragma unroll
        for (int s = 0; s < 8; ++s) {
            int G = t + s * 256;            // 0..2047
            int a = G >> 4, g = G & 15;     // 16 granules of 8 bf16 per row
            uint4 w = *(const uint4*)&Wds[a * 136 + g * 8];
            *(uint4*)&dst[a * 128 + g * 8] = w;
        }
    } else if (bid < 128) {
        const int v  = (bid - 96) >> 1;
        const int ah = (bid - 96) & 1;
        const int a  = ah * 64 + (t >> 2);
        const int q  = t & 3;
        const float* wu = Wu + (size_t)v * AA * HH + (size_t)a * HH;
        float s0 = 0.f, s1 = 0.f;
        #pragma unroll 4
        for (int h = q * 192; h < q * 192 + 192; h += 4) {
            float4 w  = *(const float4*)&wu[h];
            float4 c0 = *(const float4*)&Wc[h];
            float4 c1 = *(const float4*)&Wc[HH + h];
            s0 += w.x * c0.x + w.y * c0.y + w.z * c0.z + w.w * c0.w;
            s1 += w.x * c1.x + w.y * c1.y + w.z * c1.z + w.w * c1.w;
        }
        sp0[t] = s0; sp1[t] = s1;
        __syncthreads();
        if (t < 64) {
            float r0 = sp0[t * 4] + sp0[t * 4 + 1] + sp0[t * 4 + 2] + sp0[t * 4 + 3];
            float r1 = sp1[t * 4] + sp1[t * 4 + 1] + sp1[t * 4 + 2] + sp1[t * 4 + 3];
            int aa = ah * 64 + t;
            Wuc[(v * AA + aa) * LL + 0] = r0;
            Wuc[(v * AA + aa) * LL + 1] = r1;
        }
    } else if (bid == 128) {
        const int pair = t >> 3, seg = t & 7;
        const int v = pair >> 1, l = pair & 1;
        float s = 0.f;
        const float* bv = bu + (size_t)v * HH;
        for (int h = seg * 96; h < seg * 96 + 96; ++h) s += bv[h] * Wc[l * HH + h];
        sp0[t] = s;
        __syncthreads();
        if (t < 32) {
            float r = 0.f;
            #pragma unroll
            for (int i = 0; i < 8; ++i) r += sp0[t * 8 + i];
            buc[t] = r;   // t = v*2 + l
        }
    } else {
        if (t < VV) hist[t] = 0;
        __syncthreads();
        for (int b = t; b < BB; b += 256) atomicAdd(&hist[variety_ids[b]], 1);
        __syncthreads();
        if (t == 0) {
            int s = 0;
            for (int i = 0; i < VV; ++i) { hoff[i] = s; s += hist[i]; }
            hoff[VV] = s;
            for (int i = 0; i <= VV; ++i) ws_i[WS_OFFS + i] = hoff[i];
        }
        __syncthreads();
        if (t < VV) hcur[t] = hoff[t];
        __syncthreads();
        for (int b = t; b < BB; b += 256) {
            int v = variety_ids[b];
            int p = atomicAdd(&hcur[v], 1);
            ws_i[WS_ROWS + p] = b;
        }
    }
}

// ---------------- K2: fully fused — down-proj MFMA (full K) + gelu + Wuc + x@Wc^T + out
// 64-row tiles; waves: wr in {0,32}, wc in {0,64}. The 16-col WcB side tile
// (cols 0,1 = Wc, rest 0) gives x@Wc^T via one extra MFMA on wc==0 waves.
__global__ __launch_bounds__(256) void k_main(
    const float* __restrict__ last_hidden,
    const int*   __restrict__ ws_i,
    const float* __restrict__ bd,   // (V, A)
    const float* __restrict__ Wc,   // (L, H)
    const float* __restrict__ bc,   // (L,)
    float* __restrict__ out)        // (B, L)
{
    __shared__ __align__(16) unsigned short Xs[MT * 136];    // [row][k], pad 8
    __shared__ __align__(16) unsigned short Wds[128 * 136];  // [a][k]  (reused as p_part)
    __shared__ __align__(16) unsigned short WcB[16 * 136];   // side B tile
    __shared__ int srows[MT];
    __shared__ float xc[MT * LL];

    const int* offs = ws_i + WS_OFFS;
    const int* rows = ws_i + WS_ROWS;
    const float* Wuc = (const float*)(ws_i + WS_WUC);
    const float* buc = (const float*)(ws_i + WS_BUC);
    const unsigned short* wdp = (const unsigned short*)(ws_i + WS_WDP);
    const int t = threadIdx.x;

    // tile -> (variety, local tile)
    const int rt = blockIdx.x;
    int v = -1, tloc = 0, cnt = 0, obase = 0, acc_t = 0;
    for (int vv = 0; vv < VV; ++vv) {
        int c  = offs[vv + 1] - offs[vv];
        int nt = (c + MT - 1) / MT;
        if (rt < acc_t + nt) {
            v = vv; tloc = rt - acc_t;
            cnt = c - tloc * MT; if (cnt > MT) cnt = MT;
            obase = offs[vv];
            break;
        }
        acc_t += nt;
    }
    if (v < 0) return;

    if (t < MT) {
        int rr = t < cnt ? t : cnt - 1;
        srows[t] = rows[obase + tloc * MT + rr];
    }

    const int lane = t & 63;
    const int wv_  = t >> 6;
    const int wr = (wv_ >> 1) * 32;       // row half: 0 or 32
    const int wc = (wv_ & 1) * 64;        // a half:   0 or 64
    const int m = lane & 15, quad = lane >> 4;

    float4v acc[2][4];
    float4v accx[2];
    #pragma unroll
    for (int i = 0; i < 2; ++i) {
        accx[i] = (float4v){0.f, 0.f, 0.f, 0.f};
        #pragma unroll
        for (int j = 0; j < 4; ++j)
            acc[i][j] = (float4v){0.f, 0.f, 0.f, 0.f};
    }

    for (int kc = 0; kc < NCHUNK; ++kc) {
        const int ks0 = kc * 128;
        __syncthreads();
        // stage X: 64 rows x 128 k, fp32 -> bf16
        #pragma unroll
        for (int s = 0; s < 8; ++s) {
            int idx = t + s * 256;        // 0..2047 float4 granules
            int r   = idx >> 5;           // 32 float4 per row
            int k4  = idx & 31;
            const float* xr = last_hidden + (size_t)srows[r] * TT * HH + ks0 + k4 * 4;
            float4 xv = *(const float4*)xr;
            unsigned int p0 = (unsigned)f2bf(xv.x) | ((unsigned)f2bf(xv.y) << 16);
            unsigned int p1 = (unsigned)f2bf(xv.z) | ((unsigned)f2bf(xv.w) << 16);
            *(uint2*)&Xs[r * 136 + k4 * 4] = make_uint2(p0, p1);
        }
        // stage Wd chunk (pre-transposed dense bf16): [a][128] -> [a][k] pad 136
        {
            const unsigned short* wb = wdp + (size_t)(v * NCHUNK + kc) * AA * 128;
            #pragma unroll
            for (int s = 0; s < 8; ++s) {
                int G = t + s * 256;
                int a = G >> 4, g = G & 15;
                uint4 w = *(const uint4*)&wb[a * 128 + g * 8];
                *(uint4*)&Wds[a * 136 + g * 8] = w;
            }
        }
        // stage WcB: 16 cols x 128 k; col 0/1 = Wc row, cols 2..15 = 0
        {
            int c = t >> 4, g = t & 15;   // 256 granules of 8
            uint4 w = make_uint4(0u, 0u, 0u, 0u);
            if (c < LL) {
                const float* wcr = Wc + (size_t)c * HH + ks0 + g * 8;
                float4 w0 = *(const float4*)wcr;
                float4 w1 = *(const float4*)(wcr + 4);
                w.x = (unsigned)f2bf(w0.x) | ((unsigned)f2bf(w0.y) << 16);
                w.y = (unsigned)f2bf(w0.z) | ((unsigned)f2bf(w0.w) << 16);
                w.z = (unsigned)f2bf(w1.x) | ((unsigned)f2bf(w1.y) << 16);
                w.w = (unsigned)f2bf(w1.z) | ((unsigned)f2bf(w1.w) << 16);
            }
            *(uint4*)&WcB[c * 136 + g * 8] = w;
        }
        __syncthreads();

        #pragma unroll
        for (int k0 = 0; k0 < 128; k0 += 32) {
            short8v af[2], bf[4];
            #pragma unroll
            for (int i = 0; i < 2; ++i)
                af[i] = *(const short8v*)&Xs[(wr + i * 16 + m) * 136 + k0 + quad * 8];
            #pragma unroll
            for (int j = 0; j < 4; ++j)
                bf[j] = *(const short8v*)&Wds[(wc + j * 16 + m) * 136 + k0 + quad * 8];
            #pragma unroll
            for (int i = 0; i < 2; ++i)
                #pragma unroll
                for (int j = 0; j < 4; ++j)
                    acc[i][j] = __builtin_amdgcn_mfma_f32_16x16x32_bf16(af[i], bf[j], acc[i][j], 0, 0, 0);
            if (wc == 0) {
                short8v cf = *(const short8v*)&WcB[m * 136 + k0 + quad * 8];
                #pragma unroll
                for (int i = 0; i < 2; ++i)
                    accx[i] = __builtin_amdgcn_mfma_f32_16x16x32_bf16(af[i], cf, accx[i], 0, 0, 0);
            }
        }
    }

    __syncthreads();   // all waves done reading Wds; reuse as p_part
    float* p_part = (float*)Wds;   // [row][l][slot], slot = (wc>>6)*16 + m  -> 64*2*32 fp32 = 16 KB

    // epilogue: z += bd -> gelu -> per-lane partial of sum_a h*Wuc
    {
        const int wch = wc >> 6;
        float bdv[4], w0v[4], w1v[4];
        #pragma unroll
        for (int j = 0; j < 4; ++j) {
            int a = wc + j * 16 + m;
            bdv[j] = bd[v * AA + a];
            w0v[j] = Wuc[(v * AA + a) * LL + 0];
            w1v[j] = Wuc[(v * AA + a) * LL + 1];
        }
        #pragma unroll
        for (int i = 0; i < 2; ++i) {
            #pragma unroll
            for (int reg = 0; reg < 4; ++reg) {
                int row = wr + i * 16 + quad * 4 + reg;
                float p0 = 0.f, p1 = 0.f;
                #pragma unroll
                for (int j = 0; j < 4; ++j) {
                    float h = gelu_tanh(acc[i][j][reg] + bdv[j]);
                    p0 += h * w0v[j];
                    p1 += h * w1v[j];
                }
                p_part[(row * LL + 0) * 32 + wch * 16 + m] = p0;
                p_part[(row * LL + 1) * 32 + wch * 16 + m] = p1;
            }
        }
        // classifier side-block: col m (<2) of accx is logit l = m
        if (wc == 0 && m < LL) {
            #pragma unroll
            for (int i = 0; i < 2; ++i)
                #pragma unroll
                for (int reg = 0; reg < 4; ++reg) {
                    int row = wr + i * 16 + quad * 4 + reg;
                    xc[row * LL + m] = accx[i][reg];
                }
        }
    }
    __syncthreads();

    // final: one thread per (row, l)
    if (t < MT * LL) {
        int row = t >> 1, l = t & 1;
        if (row < cnt) {
            float s = 0.f;
            #pragma unroll
            for (int k = 0; k < 32; ++k) s += p_part[(row * LL + l) * 32 + k];
            int gr = srows[row];
            out[(size_t)gr * LL + l] = s + xc[row * LL + l] + buc[v * LL + l] + bc[l];
        }
    }
}

extern "C" void kernel_launch(void* const* d_in, const int* in_sizes, int n_in,
                              void* d_out, int out_size, void* d_ws, size_t ws_size,
                              hipStream_t stream) {
    const float* last_hidden = (const float*)d_in[0];
    const int*   variety_ids = (const int*)d_in[2];
    const float* Wd = (const float*)d_in[3];
    const float* bd = (const float*)d_in[4];
    const float* Wu = (const float*)d_in[5];
    const float* bu = (const float*)d_in[6];
    const float* Wc = (const float*)d_in[7];
    const float* bc = (const float*)d_in[8];
    float* out = (float*)d_out;

    int* ws_i = (int*)d_ws;

    k_prep<<<130, 256, 0, stream>>>(variety_ids, Wd, Wu, bu, Wc, ws_i);
    // max tiles = sum_v ceil(cnt_v/64) <= 4096/64 + 15 = 79
    k_main<<<79, 256, 0, stream>>>(last_hidden, ws_i, bd, Wc, bc, out);
}

// Round 7
// 271.174 us; speedup vs baseline: 1.0318x; 1.0318x over previous
//
#include <hip/hip_runtime.h>
#include <hip/hip_bf16.h>

// Problem constants
#define BB 4096
#define TT 16
#define HH 768
#define AA 128
#define VV 16
#define LL 2
#define NCHUNK 6        // K chunks of 128 (full K per block)
#define MT 16           // rows per tile (parallelism: up to 271 blocks)

typedef __attribute__((ext_vector_type(8))) short short8v;   // 8 bf16 (4 VGPRs)
typedef __attribute__((ext_vector_type(4))) float float4v;   // MFMA C/D frag

// ws layout (int indices into d_ws):
//  [0..16]       offs (int)     bucket offsets
//  [64..4159]    rows (int)     bucketed row ids
//  [4160..8255]  Wuc  (float)   [V][A][L] = Wu@Wc^T
//  [8256..8287]  buc  (float)   [V][L]    = bu@Wc^T
//  [8448..]      Wdp  (ushort)  [V][6][A][128] bf16 transposed Wd (dense)
#define WS_OFFS 0
#define WS_ROWS 64
#define WS_WUC  4160
#define WS_BUC  8256
#define WS_WDP  8448

__device__ __forceinline__ unsigned short f2bf(float f) {
    __hip_bfloat16 h = __float2bfloat16(f);   // RNE
    return *reinterpret_cast<unsigned short*>(&h);
}

__device__ __forceinline__ float gelu_tanh(float z) {
    float y = 0.7978845608028654f * (z + 0.044715f * z * z * z);
    y = fminf(fmaxf(y, -15.f), 15.f);
    float e = __expf(2.f * y);
    float th = (e - 1.f) / (e + 1.f);
    return 0.5f * z * (1.f + th);
}

// ---------------- K1: prep
// blocks 0..95    : Wdp[v][kc] = bf16 transpose of Wd chunk
// blocks 96..223  : Wuc — 128 blocks, 16 a-columns each (16 thr/col)
// block 224       : buc[v][l] = bu[v] @ Wc^T
// block 225       : bucket rows by variety
__global__ __launch_bounds__(256) void k_prep(
    const int*   __restrict__ variety_ids,
    const float* __restrict__ Wd,   // (V, H, A)
    const float* __restrict__ Wu,   // (V, A, H)
    const float* __restrict__ bu,   // (V, H)
    const float* __restrict__ Wc,   // (L, H)
    int* __restrict__ ws_i)
{
    __shared__ __align__(16) unsigned short Wds[128 * 136];
    __shared__ float sp0[256], sp1[256];
    __shared__ int hist[VV], hoff[VV + 1], hcur[VV];

    const int t = threadIdx.x;
    const int bid = blockIdx.x;
    unsigned short* wdp = (unsigned short*)(ws_i + WS_WDP);
    float* Wuc = (float*)(ws_i + WS_WUC);
    float* buc = (float*)(ws_i + WS_BUC);

    if (bid < 96) {
        // ---- Wd chunk transpose + convert: global [k][a] -> [a][k] ----
        const int v = bid / NCHUNK, kc = bid % NCHUNK;
        const float* wd = Wd + (size_t)v * HH * AA;
        const int ks0 = kc * 128;
        #pragma unroll
        for (int s = 0; s < 16; ++s) {
            int idx = t + s * 256;
            int hl  = idx >> 5;
            int a4  = idx & 31;
            float4 wv = *(const float4*)(wd + (size_t)(ks0 + hl) * AA + a4 * 4);
            Wds[(a4 * 4 + 0) * 136 + hl] = f2bf(wv.x);
            Wds[(a4 * 4 + 1) * 136 + hl] = f2bf(wv.y);
            Wds[(a4 * 4 + 2) * 136 + hl] = f2bf(wv.z);
            Wds[(a4 * 4 + 3) * 136 + hl] = f2bf(wv.w);
        }
        __syncthreads();
        unsigned short* dst = wdp + (size_t)(v * NCHUNK + kc) * AA * 128;
        #pragma unroll
        for (int s = 0; s < 8; ++s) {
            int G = t + s * 256;            // 0..2047
            int a = G >> 4, g = G & 15;     // 16 granules of 8 bf16 per row
            uint4 w = *(const uint4*)&Wds[a * 136 + g * 8];
            *(uint4*)&dst[a * 128 + g * 8] = w;
        }
    } else if (bid < 224) {
        // ---- Wuc: block handles (v, 16-a group); 16 threads per column ----
        const int v = (bid - 96) >> 3;
        const int g = (bid - 96) & 7;
        const int a_loc = t >> 4;           // 0..15
        const int q     = t & 15;           // h segment
        const int a = g * 16 + a_loc;
        const float* wu = Wu + (size_t)v * AA * HH + (size_t)a * HH;
        float s0 = 0.f, s1 = 0.f;
        #pragma unroll 4
        for (int h = q * 48; h < q * 48 + 48; h += 4) {
            float4 w  = *(const float4*)&wu[h];
            float4 c0 = *(const float4*)&Wc[h];
            float4 c1 = *(const float4*)&Wc[HH + h];
            s0 += w.x * c0.x + w.y * c0.y + w.z * c0.z + w.w * c0.w;
            s1 += w.x * c1.x + w.y * c1.y + w.z * c1.z + w.w * c1.w;
        }
        sp0[a_loc * 16 + q] = s0;
        sp1[a_loc * 16 + q] = s1;
        __syncthreads();
        if (t < 16) {
            float r0 = 0.f, r1 = 0.f;
            #pragma unroll
            for (int i = 0; i < 16; ++i) { r0 += sp0[t * 16 + i]; r1 += sp1[t * 16 + i]; }
            int aa = g * 16 + t;
            Wuc[(v * AA + aa) * LL + 0] = r0;
            Wuc[(v * AA + aa) * LL + 1] = r1;
        }
    } else if (bid == 224) {
        // ---- buc[v][l] : 32 pairs x 8 h-segments ----
        const int pair = t >> 3, seg = t & 7;
        const int v = pair >> 1, l = pair & 1;
        float s = 0.f;
        const float* bv = bu + (size_t)v * HH;
        for (int h = seg * 96; h < seg * 96 + 96; ++h) s += bv[h] * Wc[l * HH + h];
        sp0[t] = s;
        __syncthreads();
        if (t < 32) {
            float r = 0.f;
            #pragma unroll
            for (int i = 0; i < 8; ++i) r += sp0[t * 8 + i];
            buc[t] = r;   // t = v*2 + l
        }
    } else {
        // ---- bucketing ----
        if (t < VV) hist[t] = 0;
        __syncthreads();
        for (int b = t; b < BB; b += 256) atomicAdd(&hist[variety_ids[b]], 1);
        __syncthreads();
        if (t == 0) {
            int s = 0;
            for (int i = 0; i < VV; ++i) { hoff[i] = s; s += hist[i]; }
            hoff[VV] = s;
            for (int i = 0; i <= VV; ++i) ws_i[WS_OFFS + i] = hoff[i];
        }
        __syncthreads();
        if (t < VV) hcur[t] = hoff[t];
        __syncthreads();
        for (int b = t; b < BB; b += 256) {
            int v = variety_ids[b];
            int p = atomicAdd(&hcur[v], 1);
            ws_i[WS_ROWS + p] = b;
        }
    }
}

// ---------------- K2: fused — down-proj MFMA (full K) + gelu + Wuc + x@Wc^T + out
// 16-row tiles, 4 waves each owning a 32-wide a-quarter. Wave 0 also runs the
// WcB side-MFMA (cols 0,1 = Wc) producing x@Wc^T for the tile's rows.
__global__ __launch_bounds__(256) void k_main(
    const float* __restrict__ last_hidden,
    const int*   __restrict__ ws_i,
    const float* __restrict__ bd,   // (V, A)
    const float* __restrict__ Wc,   // (L, H)
    const float* __restrict__ bc,   // (L,)
    float* __restrict__ out)        // (B, L)
{
    __shared__ __align__(16) unsigned short Xs[MT * 136];    // [row][k], pad 8
    __shared__ __align__(16) unsigned short Wds[128 * 136];  // [a][k]  (reused as p_part)
    __shared__ __align__(16) unsigned short WcB[16 * 136];   // side B tile
    __shared__ int srows[MT];
    __shared__ float xc[MT * LL];

    const int* offs = ws_i + WS_OFFS;
    const int* rows = ws_i + WS_ROWS;
    const float* Wuc = (const float*)(ws_i + WS_WUC);
    const float* buc = (const float*)(ws_i + WS_BUC);
    const unsigned short* wdp = (const unsigned short*)(ws_i + WS_WDP);
    const int t = threadIdx.x;

    // tile -> (variety, local tile)
    const int rt = blockIdx.x;
    int v = -1, tloc = 0, cnt = 0, obase = 0, acc_t = 0;
    for (int vv = 0; vv < VV; ++vv) {
        int c  = offs[vv + 1] - offs[vv];
        int nt = (c + MT - 1) / MT;
        if (rt < acc_t + nt) {
            v = vv; tloc = rt - acc_t;
            cnt = c - tloc * MT; if (cnt > MT) cnt = MT;
            obase = offs[vv];
            break;
        }
        acc_t += nt;
    }
    if (v < 0) return;

    if (t < MT) {
        int rr = t < cnt ? t : cnt - 1;
        srows[t] = rows[obase + tloc * MT + rr];
    }

    const int lane = t & 63;
    const int wv_  = t >> 6;              // 0..3: a-quarter
    const int ac0  = wv_ * 32;
    const int m = lane & 15, quad = lane >> 4;

    float4v acc[2];                        // a-cols ac0 + j*16 + m
    float4v accx;                          // classifier side (wave 0)
    acc[0] = (float4v){0.f, 0.f, 0.f, 0.f};
    acc[1] = (float4v){0.f, 0.f, 0.f, 0.f};
    accx   = (float4v){0.f, 0.f, 0.f, 0.f};

    for (int kc = 0; kc < NCHUNK; ++kc) {
        const int ks0 = kc * 128;
        __syncthreads();
        // stage X: 16 rows x 128 k, fp32 -> bf16 (512 float4 granules)
        #pragma unroll
        for (int s = 0; s < 2; ++s) {
            int idx = t + s * 256;        // 0..511
            int r   = idx >> 5;
            int k4  = idx & 31;
            const float* xr = last_hidden + (size_t)srows[r] * TT * HH + ks0 + k4 * 4;
            float4 xv = *(const float4*)xr;
            unsigned int p0 = (unsigned)f2bf(xv.x) | ((unsigned)f2bf(xv.y) << 16);
            unsigned int p1 = (unsigned)f2bf(xv.z) | ((unsigned)f2bf(xv.w) << 16);
            *(uint2*)&Xs[r * 136 + k4 * 4] = make_uint2(p0, p1);
        }
        // stage Wd chunk (pre-transposed dense bf16): [a][128] -> [a][k] pad 136
        {
            const unsigned short* wb = wdp + (size_t)(v * NCHUNK + kc) * AA * 128;
            #pragma unroll
            for (int s = 0; s < 8; ++s) {
                int G = t + s * 256;
                int a = G >> 4, g = G & 15;
                uint4 w = *(const uint4*)&wb[a * 128 + g * 8];
                *(uint4*)&Wds[a * 136 + g * 8] = w;
            }
        }
        // stage WcB: 16 cols x 128 k; col 0/1 = Wc row, cols 2..15 = 0
        {
            int c = t >> 4, g = t & 15;   // 256 granules of 8
            uint4 w = make_uint4(0u, 0u, 0u, 0u);
            if (c < LL) {
                const float* wcr = Wc + (size_t)c * HH + ks0 + g * 8;
                float4 w0 = *(const float4*)wcr;
                float4 w1 = *(const float4*)(wcr + 4);
                w.x = (unsigned)f2bf(w0.x) | ((unsigned)f2bf(w0.y) << 16);
                w.y = (unsigned)f2bf(w0.z) | ((unsigned)f2bf(w0.w) << 16);
                w.z = (unsigned)f2bf(w1.x) | ((unsigned)f2bf(w1.y) << 16);
                w.w = (unsigned)f2bf(w1.z) | ((unsigned)f2bf(w1.w) << 16);
            }
            *(uint4*)&WcB[c * 136 + g * 8] = w;
        }
        __syncthreads();

        #pragma unroll
        for (int k0 = 0; k0 < 128; k0 += 32) {
            short8v af = *(const short8v*)&Xs[m * 136 + k0 + quad * 8];
            short8v bf0 = *(const short8v*)&Wds[(ac0 + m) * 136 + k0 + quad * 8];
            short8v bf1 = *(const short8v*)&Wds[(ac0 + 16 + m) * 136 + k0 + quad * 8];
            acc[0] = __builtin_amdgcn_mfma_f32_16x16x32_bf16(af, bf0, acc[0], 0, 0, 0);
            acc[1] = __builtin_amdgcn_mfma_f32_16x16x32_bf16(af, bf1, acc[1], 0, 0, 0);
            if (wv_ == 0) {
                short8v cf = *(const short8v*)&WcB[m * 136 + k0 + quad * 8];
                accx = __builtin_amdgcn_mfma_f32_16x16x32_bf16(af, cf, accx, 0, 0, 0);
            }
        }
    }

    __syncthreads();   // all waves done reading Wds; reuse as p_part
    float* p_part = (float*)Wds;   // [row][l][slot], slot = wv_*16 + m  (64 slots) -> 8 KB

    // epilogue: z += bd -> gelu -> per-lane partial of sum_a h*Wuc
    {
        float bdv[2], w0v[2], w1v[2];
        #pragma unroll
        for (int j = 0; j < 2; ++j) {
            int a = ac0 + j * 16 + m;
            bdv[j] = bd[v * AA + a];
            w0v[j] = Wuc[(v * AA + a) * LL + 0];
            w1v[j] = Wuc[(v * AA + a) * LL + 1];
        }
        #pragma unroll
        for (int reg = 0; reg < 4; ++reg) {
            int row = quad * 4 + reg;
            float p0 = 0.f, p1 = 0.f;
            #pragma unroll
            for (int j = 0; j < 2; ++j) {
                float h = gelu_tanh(acc[j][reg] + bdv[j]);
                p0 += h * w0v[j];
                p1 += h * w1v[j];
            }
            p_part[(row * LL + 0) * 64 + wv_ * 16 + m] = p0;
            p_part[(row * LL + 1) * 64 + wv_ * 16 + m] = p1;
        }
        // classifier side-block: col m (<2) of accx is logit l = m
        if (wv_ == 0 && m < LL) {
            #pragma unroll
            for (int reg = 0; reg < 4; ++reg) {
                int row = quad * 4 + reg;
                xc[row * LL + m] = accx[reg];
            }
        }
    }
    __syncthreads();

    // final: one thread per (row, l)
    if (t < MT * LL) {
        int row = t >> 1, l = t & 1;
        if (row < cnt) {
            float s = 0.f;
            #pragma unroll
            for (int k = 0; k < 64; ++k) s += p_part[(row * LL + l) * 64 + k];
            int gr = srows[row];
            out[(size_t)gr * LL + l] = s + xc[row * LL + l] + buc[v * LL + l] + bc[l];
        }
    }
}

extern "C" void kernel_launch(void* const* d_in, const int* in_sizes, int n_in,
                              void* d_out, int out_size, void* d_ws, size_t ws_size,
                              hipStream_t stream) {
    const float* last_hidden = (const float*)d_in[0];
    const int*   variety_ids = (const int*)d_in[2];
    const float* Wd = (const float*)d_in[3];
    const float* bd = (const float*)d_in[4];
    const float* Wu = (const float*)d_in[5];
    const float* bu = (const float*)d_in[6];
    const float* Wc = (const float*)d_in[7];
    const float* bc = (const float*)d_in[8];
    float* out = (float*)d_out;

    int* ws_i = (int*)d_ws;

    k_prep<<<226, 256, 0, stream>>>(variety_ids, Wd, Wu, bu, Wc, ws_i);
    // max tiles = sum_v ceil(cnt_v/16) <= 4096/16 + 15 = 271
    k_main<<<271, 256, 0, stream>>>(last_hidden, ws_i, bd, Wc, bc, out);
}